// Round 7
// baseline (314.161 us; speedup 1.0000x reference)
//
#include <hip/hip_runtime.h>

#define BB 64
#define LL 512
#define TT 52
#define START_TAG 50
#define END_TAG 51

// LDS-only barrier: orders LDS + rendezvous WITHOUT draining vmcnt (feats
// prefetch loads stay in flight across steps).
__device__ __forceinline__ void lds_barrier() {
    __asm__ __volatile__("s_waitcnt lgkmcnt(0)\n\ts_barrier" ::: "memory");
}
__device__ __forceinline__ unsigned umin32(unsigned a, unsigned b) { return a < b ? a : b; }

// Block = 256 threads = 4 waves per batch element; wave w owns i in [13w,13w+13).
// SOFTWARE-PIPELINED step: only the VALUE travels on the critical path
// (readlane->add->max3 tree->b32 write->barrier->4x b32 read->max). Backpointer
// work for step t-1 (index extraction, cross-wave resolve, s_bp byte) and the
// f+c precompute for t+1 run as filler inside step t's stall windows.
// s_val stride-5 padding: write bank (5j+w)%32 and reads (5j+k)%32 conflict-free.
// Exactness: values are the reference's (f+c[i])+P[i] bit-exact; max is order-
// independent; argmax = smallest index with bits==max-bits == first-max-wins
// == jnp.argmax (fp ties share bits; +-0 maxima measure-zero).
__launch_bounds__(256, 1)
__global__ void viterbi_kernel(const float* __restrict__ feats,
                               const int* __restrict__ mask,
                               const float* __restrict__ trans,
                               int* __restrict__ out) {
    const int b    = blockIdx.x;
    const int tid  = threadIdx.x;
    const int lane = tid & 63;
    const int w    = tid >> 6;
    const int wbase = w * 13;

    __shared__ float s_val[2][64 * 5 + 4];     // [buf][j*5 + w], conflict-free
    __shared__ unsigned char s_idx[2][256];    // [buf][j*4 + w] local-idx bytes
    __shared__ unsigned char s_bp[LL * TT];    // backpointers (26624 B)
    __shared__ int s_tags[LL];
    __shared__ unsigned char s_map[8 * 52];
    __shared__ int s_ent[8];

    // ---- length n = sum(mask[b,:]) ----
    int partial = 0;
    const int* mrow = mask + b * LL;
    #pragma unroll
    for (int k = 0; k < LL / 64; ++k) partial += mrow[lane + 64 * k];
    #pragma unroll
    for (int off = 32; off >= 1; off >>= 1) partial += __shfl_xor(partial, off, 64);
    const int n = partial;  // uniform, in [256, 512]

    // ---- per-wave transition slice ----
    float creg[13];
    #pragma unroll
    for (int q = 0; q < 13; ++q)
        creg[q] = (lane < TT) ? trans[(wbase + q) * TT + lane] : 0.0f;
    const float tE = (lane < TT) ? trans[lane * TT + END_TAG] : 0.0f;

    const float* frow = feats + (size_t)b * LL * TT;

    // ---- P0 in-register, every wave ----
    float bestP = (lane < TT) ? (frow[lane] + trans[START_TAG * TT + lane]) : -3.0e38f;

    #pragma unroll
    for (int k = 0; k < LL / 256; ++k) s_tags[tid + 256 * k] = 0;

    const int vslot = lane * 5 + w;

    // ---- fc for t=1; feats ring holds rows t+1..t+4 ----
    float f1 = (lane < TT) ? frow[TT + lane] : 0.0f;
    float fcur[13];
    #pragma unroll
    for (int q = 0; q < 13; ++q) fcur[q] = f1 + creg[q];
    float fr[4];
    #pragma unroll
    for (int d = 0; d < 4; ++d) {
        int tt = 2 + d; if (tt > LL - 1) tt = LL - 1;
        fr[d] = (lane < TT) ? frow[tt * TT + lane] : 0.0f;
    }

    // pipelined prev-step state
    float bvP[13];
    #pragma unroll
    for (int q = 0; q < 13; ++q) bvP[q] = 0.0f;
    float MP = 0.0f;
    float v0P = 0.0f, v1P = 0.0f, v2P = 0.0f, v3P = 0.0f;

    auto step = [&](int t, int d_ring, int rsel) {
        const int buf = t & 1;
        const float Pprev = bestP;              // combined value of step t-1

        // ---- critical value path ----
        float bv[13];
        #pragma unroll
        for (int q = 0; q < 13; ++q) {
            float pq = __int_as_float(__builtin_amdgcn_readlane(__float_as_int(bestP), wbase + q));
            bv[q] = fcur[q] + pq;               // (f + c[i]) + P[i], exact order
        }
        float m0 = fmaxf(fmaxf(bv[0], bv[1]), bv[2]);
        float m1 = fmaxf(fmaxf(bv[3], bv[4]), bv[5]);
        float m2 = fmaxf(fmaxf(bv[6], bv[7]), bv[8]);
        float m3 = fmaxf(fmaxf(bv[9], bv[10]), bv[11]);
        float M  = fmaxf(fmaxf(fmaxf(m0, m1), fmaxf(m2, m3)), bv[12]);
        s_val[buf][vslot] = M;

        // ---- filler A (pre-barrier): index extraction for step t-1 ----
        {
            unsigned mb = __float_as_uint(MP);
            unsigned kk[13];
            #pragma unroll
            for (int q = 0; q < 13; ++q)
                kk[q] = (umin32(__float_as_uint(bvP[q]) ^ mb, 1u) << 6) | (unsigned)q;
            unsigned k0 = umin32(umin32(kk[0], kk[1]), kk[2]);
            unsigned k1 = umin32(umin32(kk[3], kk[4]), kk[5]);
            unsigned k2 = umin32(umin32(kk[6], kk[7]), kk[8]);
            unsigned k3 = umin32(umin32(kk[9], kk[10]), kk[11]);
            unsigned km = umin32(umin32(umin32(k0, k1), umin32(k2, k3)), kk[12]);
            s_idx[buf ^ 1][(lane << 2) + w] = (unsigned char)(km & 63u);
        }

        lds_barrier();

        // ---- critical combine: 4 conflict-free b32 reads + max ----
        float v0 = s_val[buf][lane * 5 + 0];
        float v1 = s_val[buf][lane * 5 + 1];
        float v2 = s_val[buf][lane * 5 + 2];
        float v3 = s_val[buf][lane * 5 + 3];
        float nbest = fmaxf(fmaxf(v0, v1), fmaxf(v2, v3));

        // ---- filler B (post-barrier): resolve bp row t-1 (rotated wave) ----
        if (t >= 2 && w == rsel) {
            unsigned idx4 = *(const unsigned*)(s_idx[buf ^ 1] + (lane << 2));
            unsigned cb = __float_as_uint(Pprev);
            unsigned a0 = (umin32(__float_as_uint(v0P) ^ cb, 1u) << 2) | 0u;
            unsigned a1 = (umin32(__float_as_uint(v1P) ^ cb, 1u) << 2) | 1u;
            unsigned a2 = (umin32(__float_as_uint(v2P) ^ cb, 1u) << 2) | 2u;
            unsigned a3 = (umin32(__float_as_uint(v3P) ^ cb, 1u) << 2) | 3u;
            unsigned wm = umin32(umin32(a0, a1), umin32(a2, a3)) & 3u;
            unsigned loc = (idx4 >> (wm << 3)) & 63u;
            if (lane < TT) s_bp[(t - 1) * TT + lane] = (unsigned char)(wm * 13u + loc);
        }

        bestP = nbest;
        // save prev-step state
        #pragma unroll
        for (int q = 0; q < 13; ++q) bvP[q] = bv[q];
        MP = M; v0P = v0; v1P = v1; v2P = v2; v3P = v3;

        // fc for step t+1 + ring refill (filler)
        float fN = fr[d_ring];
        #pragma unroll
        for (int q = 0; q < 13; ++q) fcur[q] = fN + creg[q];
        int tt = t + 5; if (tt > LL - 1) tt = LL - 1;
        fr[d_ring] = (lane < TT) ? frow[tt * TT + lane] : 0.0f;
    };

    int t = 1;
    for (; t + 3 < n; t += 4) {        // t ≡ 1 (mod 4): rsel = d
        step(t, 0, 0); step(t + 1, 1, 1); step(t + 2, 2, 2); step(t + 3, 3, 3);
    }
    for (int d = 0; t < n; ++t, ++d) step(t, d, (t - 1) & 3);   // tail <= 3

    // ---- flush: bp row n-1 ----
    {
        unsigned mb = __float_as_uint(MP);
        unsigned kk[13];
        #pragma unroll
        for (int q = 0; q < 13; ++q)
            kk[q] = (umin32(__float_as_uint(bvP[q]) ^ mb, 1u) << 6) | (unsigned)q;
        unsigned k0 = umin32(umin32(kk[0], kk[1]), kk[2]);
        unsigned k1 = umin32(umin32(kk[3], kk[4]), kk[5]);
        unsigned k2 = umin32(umin32(kk[6], kk[7]), kk[8]);
        unsigned k3 = umin32(umin32(kk[9], kk[10]), kk[11]);
        unsigned km = umin32(umin32(umin32(k0, k1), umin32(k2, k3)), kk[12]);
        s_idx[0][(lane << 2) + w] = (unsigned char)(km & 63u);
    }
    __syncthreads();
    if (w == 0) {
        unsigned idx4 = *(const unsigned*)(s_idx[0] + (lane << 2));
        unsigned cb = __float_as_uint(bestP);
        unsigned a0 = (umin32(__float_as_uint(v0P) ^ cb, 1u) << 2) | 0u;
        unsigned a1 = (umin32(__float_as_uint(v1P) ^ cb, 1u) << 2) | 1u;
        unsigned a2 = (umin32(__float_as_uint(v2P) ^ cb, 1u) << 2) | 2u;
        unsigned a3 = (umin32(__float_as_uint(v3P) ^ cb, 1u) << 2) | 3u;
        unsigned wm = umin32(umin32(a0, a1), umin32(a2, a3)) & 3u;
        unsigned loc = (idx4 >> (wm << 3)) & 63u;
        if (lane < TT) s_bp[(n - 1) * TT + lane] = (unsigned char)(wm * 13u + loc);
    }

    // ---- pointer0 = argmax_i ( P_{n-1}[i] + trans[i,END] ), min-index tie ----
    float lv = (lane < TT) ? (bestP + tE) : -3.0e38f;
    int li = lane;
    #pragma unroll
    for (int off = 32; off >= 1; off >>= 1) {
        float ov = __shfl_xor(lv, off, 64);
        int   oi = __shfl_xor(li, off, 64);
        if (ov > lv || (ov == lv && oi < li)) { lv = ov; li = oi; }
    }
    const int ptr0 = li;

    __syncthreads();

    // ---- backtrace: 8-chunk two-phase parallel pointer chase ----
    const int W  = n - 1;
    const int Sc = (W + 7) >> 3;
    {
        int v0 = tid;
        int k0 = v0 / 52, y0 = v0 - k0 * 52;
        int v1 = tid + 256;
        bool a1 = (v1 < 416);
        int k1 = a1 ? v1 / 52 : 7, y1 = a1 ? (v1 - k1 * 52) : 0;
        int s0a = k0 * Sc, s1a = min(s0a + Sc, W);
        int s0b = k1 * Sc, s1b = min(s0b + Sc, W);
        int xa = y0, xb = y1;
        for (int s = 0; s < Sc; ++s) {
            int ga = s0a + s, gb = s0b + s;
            if (ga < s1a) xa = s_bp[(n - 1 - ga) * TT + xa];
            if (gb < s1b) xb = s_bp[(n - 1 - gb) * TT + xb];
        }
        s_map[k0 * 52 + y0] = (unsigned char)xa;
        if (a1) s_map[k1 * 52 + y1] = (unsigned char)xb;
    }
    __syncthreads();
    if (tid == 0) {
        int e = ptr0; s_ent[0] = e;
        #pragma unroll
        for (int k = 1; k < 8; ++k) { e = s_map[(k - 1) * 52 + e]; s_ent[k] = e; }
        s_tags[n - 1] = ptr0;
        s_tags[LL - 1] = ptr0;   // reference quirk: decode[L-1] = pointer0 always
    }
    __syncthreads();
    if (tid < 8) {
        int k = tid;
        int x = s_ent[k];
        int ss0 = k * Sc, ss1 = min(ss0 + Sc, W);
        for (int s = ss0; s < ss1; ++s) {
            x = s_bp[(n - 1 - s) * TT + x];
            s_tags[n - 2 - s] = x;
        }
    }
    __syncthreads();

    // ---- coalesced output write ----
    int* orow = out + b * LL;
    #pragma unroll
    for (int k = 0; k < LL / 256; ++k) orow[tid + 256 * k] = s_tags[tid + 256 * k];
}

extern "C" void kernel_launch(void* const* d_in, const int* in_sizes, int n_in,
                              void* d_out, int out_size, void* d_ws, size_t ws_size,
                              hipStream_t stream) {
    const float* feats = (const float*)d_in[0];
    const int*   mask  = (const int*)d_in[1];
    const float* trans = (const float*)d_in[2];
    int* out = (int*)d_out;
    viterbi_kernel<<<dim3(BB), dim3(256), 0, stream>>>(feats, mask, trans, out);
}

// Round 8
// 269.229 us; speedup vs baseline: 1.1669x; 1.1669x over previous
//
#include <hip/hip_runtime.h>

#define BB 64
#define LL 512
#define TT 52
#define START_TAG 50
#define END_TAG 51

// LDS-only barrier: orders LDS + rendezvous WITHOUT draining vmcnt.
__device__ __forceinline__ void lds_barrier() {
    __asm__ __volatile__("s_waitcnt lgkmcnt(0)\n\ts_barrier" ::: "memory");
}
__device__ __forceinline__ unsigned umin32(unsigned a, unsigned b) { return a < b ? a : b; }

// Block = 256 threads = 4 waves per batch element; wave w owns i in [13w,13w+13).
// R8 experiment: ZERO global-memory ops in the step loop. feats staged to LDS
// in 64-step chunks, double-buffered; refill once per segment, consumed 63
// steps later (latency fully amortized). Per step f = one ds_read_b32 issued
// one step early. Step body otherwise identical to R6 (best known).
// Exactness: values are the reference's (f+c[i])+P[i] bit-exact; max is order-
// independent; argmax = smallest index with bits==max-bits == first-max-wins
// == jnp.argmax (fp ties share bits; +-0 maxima measure-zero).
__launch_bounds__(256, 1)
__global__ void viterbi_kernel(const float* __restrict__ feats,
                               const int* __restrict__ mask,
                               const float* __restrict__ trans,
                               int* __restrict__ out) {
    const int b    = blockIdx.x;
    const int tid  = threadIdx.x;
    const int lane = tid & 63;
    const int w    = tid >> 6;
    const int wbase = w * 13;

    __shared__ float s_feat[2][64 * 52 + 64];            // chunk staging (+pad for lane>51 reads)
    __shared__ unsigned long long s_part[2][64 * 5 + 4]; // [buf][j*5 + w]
    __shared__ unsigned char s_bp[LL * TT];              // backpointers (26624 B)
    __shared__ int s_tags[LL];
    __shared__ unsigned char s_map[8 * 52];
    __shared__ int s_ent[8];

    // ---- length n = sum(mask[b,:]) ----
    int partial = 0;
    const int* mrow = mask + b * LL;
    #pragma unroll
    for (int k = 0; k < LL / 64; ++k) partial += mrow[lane + 64 * k];
    #pragma unroll
    for (int off = 32; off >= 1; off >>= 1) partial += __shfl_xor(partial, off, 64);
    const int n = partial;  // uniform, in [256, 512]

    // ---- per-wave transition slice ----
    float creg[13];
    #pragma unroll
    for (int q = 0; q < 13; ++q)
        creg[q] = (lane < TT) ? trans[(wbase + q) * TT + lane] : 0.0f;
    const float tE = (lane < TT) ? trans[lane * TT + END_TAG] : 0.0f;

    const float* frow = feats + (size_t)b * LL * TT;

    // ---- P0 in-register, every wave ----
    float bestP = (lane < TT) ? (frow[lane] + trans[START_TAG * TT + lane]) : -3.0e38f;
    // f for t=1 from global (once)
    float fcur = (lane < TT) ? frow[TT + lane] : 0.0f;

    #pragma unroll
    for (int k = 0; k < LL / 256; ++k) s_tags[tid + 256 * k] = 0;

    // ---- preload chunks 0 and 1 (rows 0..127) into LDS ----
    #pragma unroll
    for (int k = 0; k < 13; ++k) {
        int idx = k * 256 + tid;                 // [0, 3328)
        s_feat[0][idx] = frow[idx];              // rows 0..63
        s_feat[1][idx] = frow[64 * 52 + idx];    // rows 64..127
    }
    __syncthreads();

    const int slot = lane * 5 + w;

    // ---- one step (R6 body; f from register, next f via LDS) ----
    auto step = [&](int t, float f, float& fnext_out) {
        // issue next-step f read early (retires at this step's barrier)
        int tn = t + 1; if (tn > LL - 1) tn = LL - 1;
        float fnx = s_feat[(tn >> 6) & 1][(tn & 63) * 52 + lane];

        float tmp[13];
        #pragma unroll
        for (int q = 0; q < 13; ++q) tmp[q] = f + creg[q];

        float bv[13];
        #pragma unroll
        for (int q = 0; q < 13; ++q) {
            float pq = __int_as_float(__builtin_amdgcn_readlane(__float_as_int(bestP), wbase + q));
            bv[q] = tmp[q] + pq;                 // (f + c[i]) + P[i], exact order
        }

        float m0 = fmaxf(fmaxf(bv[0], bv[1]), bv[2]);
        float m1 = fmaxf(fmaxf(bv[3], bv[4]), bv[5]);
        float m2 = fmaxf(fmaxf(bv[6], bv[7]), bv[8]);
        float m3 = fmaxf(fmaxf(bv[9], bv[10]), bv[11]);
        float M  = fmaxf(fmaxf(fmaxf(m0, m1), fmaxf(m2, m3)), bv[12]);

        unsigned kk[13];
        #pragma unroll
        for (int q = 0; q < 13; ++q) {
            unsigned e  = __float_as_uint(bv[q]) ^ __float_as_uint(M);
            kk[q] = (umin32(e, 1u) << 6) | (unsigned)q;
        }
        unsigned k0 = umin32(umin32(kk[0], kk[1]), kk[2]);
        unsigned k1 = umin32(umin32(kk[3], kk[4]), kk[5]);
        unsigned k2 = umin32(umin32(kk[6], kk[7]), kk[8]);
        unsigned k3 = umin32(umin32(kk[9], kk[10]), kk[11]);
        unsigned km = umin32(umin32(umin32(k0, k1), umin32(k2, k3)), kk[12]);
        unsigned pidx = (unsigned)wbase + (km & 63u);

        const int buf = t & 1;
        unsigned long long pk = ((unsigned long long)pidx << 32)
                              | (unsigned long long)__float_as_uint(M);
        s_part[buf][slot] = pk;
        lds_barrier();   // LDS-order + rendezvous; no vmcnt drain

        unsigned long long p0 = s_part[buf][lane * 5 + 0];
        unsigned long long p1 = s_part[buf][lane * 5 + 1];
        unsigned long long p2 = s_part[buf][lane * 5 + 2];
        unsigned long long p3 = s_part[buf][lane * 5 + 3];
        float v0 = __uint_as_float((unsigned)p0);
        float v1 = __uint_as_float((unsigned)p1);
        float v2 = __uint_as_float((unsigned)p2);
        float v3 = __uint_as_float((unsigned)p3);
        float cv = fmaxf(fmaxf(v0, v1), fmaxf(v2, v3));
        unsigned cb = __float_as_uint(cv);
        unsigned c0 = (umin32(__float_as_uint(v0) ^ cb, 1u) << 6) | (unsigned)(p0 >> 32);
        unsigned c1 = (umin32(__float_as_uint(v1) ^ cb, 1u) << 6) | (unsigned)(p1 >> 32);
        unsigned c2 = (umin32(__float_as_uint(v2) ^ cb, 1u) << 6) | (unsigned)(p2 >> 32);
        unsigned c3 = (umin32(__float_as_uint(v3) ^ cb, 1u) << 6) | (unsigned)(p3 >> 32);
        unsigned ci = umin32(umin32(c0, c1), umin32(c2, c3)) & 63u;

        bestP = cv;
        if (tid < TT) s_bp[t * TT + tid] = (unsigned char)ci;
        fnext_out = fnx;
    };

    // ---- forward: segments of 64 steps; refill inactive feat buffer per segment ----
    int t = 1;
    for (int c = 0; 64 * c < n; ++c) {
        if (c >= 1) {
            int src = 64 * (c + 1);              // chunk c+1 rows
            if (src < LL) {
                const float* sp = frow + src * 52;
                float* dp = s_feat[(c + 1) & 1];
                #pragma unroll
                for (int k = 0; k < 13; ++k) {
                    int idx = k * 256 + tid;
                    dp[idx] = sp[idx];
                }
            }
        }
        int tend = 64 * (c + 1); if (tend > n) tend = n;
        for (; t + 3 < tend; t += 4) {
            step(t,     fcur, fcur);
            step(t + 1, fcur, fcur);
            step(t + 2, fcur, fcur);
            step(t + 3, fcur, fcur);
        }
        for (; t < tend; ++t) step(t, fcur, fcur);
    }

    // ---- pointer0 = argmax_i ( P_{n-1}[i] + trans[i,END] ), min-index tie ----
    float lv = (lane < TT) ? (bestP + tE) : -3.0e38f;
    int li = lane;
    #pragma unroll
    for (int off = 32; off >= 1; off >>= 1) {
        float ov = __shfl_xor(lv, off, 64);
        int   oi = __shfl_xor(li, off, 64);
        if (ov > lv || (ov == lv && oi < li)) { lv = ov; li = oi; }
    }
    const int ptr0 = li;

    __syncthreads();

    // ---- backtrace: 8-chunk two-phase parallel pointer chase ----
    const int W  = n - 1;
    const int Sc = (W + 7) >> 3;
    {
        int v0 = tid;
        int k0 = v0 / 52, y0 = v0 - k0 * 52;
        int v1 = tid + 256;
        bool a1 = (v1 < 416);
        int k1 = a1 ? v1 / 52 : 7, y1 = a1 ? (v1 - k1 * 52) : 0;
        int s0a = k0 * Sc, s1a = min(s0a + Sc, W);
        int s0b = k1 * Sc, s1b = min(s0b + Sc, W);
        int xa = y0, xb = y1;
        for (int s = 0; s < Sc; ++s) {
            int ga = s0a + s, gb = s0b + s;
            if (ga < s1a) xa = s_bp[(n - 1 - ga) * TT + xa];
            if (gb < s1b) xb = s_bp[(n - 1 - gb) * TT + xb];
        }
        s_map[k0 * 52 + y0] = (unsigned char)xa;
        if (a1) s_map[k1 * 52 + y1] = (unsigned char)xb;
    }
    __syncthreads();
    if (tid == 0) {
        int e = ptr0; s_ent[0] = e;
        #pragma unroll
        for (int k = 1; k < 8; ++k) { e = s_map[(k - 1) * 52 + e]; s_ent[k] = e; }
        s_tags[n - 1] = ptr0;
        s_tags[LL - 1] = ptr0;   // reference quirk: decode[L-1] = pointer0 always
    }
    __syncthreads();
    if (tid < 8) {
        int k = tid;
        int x = s_ent[k];
        int ss0 = k * Sc, ss1 = min(ss0 + Sc, W);
        for (int s = ss0; s < ss1; ++s) {
            x = s_bp[(n - 1 - s) * TT + x];
            s_tags[n - 2 - s] = x;
        }
    }
    __syncthreads();

    // ---- coalesced output write ----
    int* orow = out + b * LL;
    #pragma unroll
    for (int k = 0; k < LL / 256; ++k) orow[tid + 256 * k] = s_tags[tid + 256 * k];
}

extern "C" void kernel_launch(void* const* d_in, const int* in_sizes, int n_in,
                              void* d_out, int out_size, void* d_ws, size_t ws_size,
                              hipStream_t stream) {
    const float* feats = (const float*)d_in[0];
    const int*   mask  = (const int*)d_in[1];
    const float* trans = (const float*)d_in[2];
    int* out = (int*)d_out;
    viterbi_kernel<<<dim3(BB), dim3(256), 0, stream>>>(feats, mask, trans, out);
}